// Round 9
// baseline (523.998 us; speedup 1.0000x reference)
//
#include <hip/hip_runtime.h>
#include <hip/hip_bf16.h>

#define NN 100000
#define EE 1600000
#define HID 128
#define NEG 0.2f
#define CAP 64     // fixed CSR capacity per node (avg deg 16, P(deg>64) ~ 1e-19)
#define BSH 9      // coarse bucket = dst >> 9 (512 nodes/bucket)
#define NB 196     // ceil(NN / 512)
#define NNP (NB * 512)  // csr row padding (100352) so build writes are unguarded
#define CAPB 9216  // per-bucket edge capacity (mean 8192, sigma~90 -> 11 sigma)
#define EBLK 4096  // edges per bin block (391 blocks/path)
#define NBINB 391  // bin blocks per path
#define NBUILD 392 // build blocks (196 buckets x 2 paths)
#define NPROJ 512  // proj blocks in fused k_mid
#define NPREPW 208 // wprep blocks: (32768+16384+4096)/256

typedef __attribute__((ext_vector_type(8))) short short8;
typedef __attribute__((ext_vector_type(4))) float f32x4;

static __device__ __forceinline__ float bf2f(short s) {
  union { float f; unsigned u; } c;
  c.u = ((unsigned)(unsigned short)s) << 16;
  return c.f;
}

// raw v_exp_f32: computes 2^x in one instruction (no mul-by-log2e preamble).
static __device__ __forceinline__ float exp2_fast(float x) {
  float r;
  asm("v_exp_f32 %0, %1" : "=v"(r) : "v"(x));
  return r;
}

// fast tanh: 1 - 2/(2^(2x*log2e)+1); clamp keeps exp in range, rcp approx ok.
static __device__ __forceinline__ float tanh_fast(float x) {
  float a = fminf(fmaxf(x * 2.885390082f, -40.f), 40.f);  // 2*log2(e)*x
  float e = exp2_fast(a);
  float r = __builtin_amdgcn_rcpf(e + 1.f);
  return fmaf(-2.f, r, 1.f);
}

// ---------------- fused: edge binning + weight pre-transpose ----------------
// blocks [0, 782): bin edges by coarse dst bucket (two-phase, LDS-staged;
//   single-atomic register-stash form). One-phase global scatter = 220us (r2).
// blocks [782, 990): transpose proj_w / k_lin_w to bf16; build awTg — the
//   32x128 block-diagonal alpha-weight (bf16, pre-scaled by log2e) for the
//   MFMA alpha-logit computation (r6: serial shuffle butterfly was the proj
//   bottleneck). Col c = p*16 + dtype*8 + h; row k nonzero iff k>>4 == h.
__global__ __launch_bounds__(256) void k_prep(const int* __restrict__ ei0,
    const int* __restrict__ ei1, const float* __restrict__ w,
    const float* __restrict__ kw,
    const float* __restrict__ a0s, const float* __restrict__ a0d,
    const float* __restrict__ a1s, const float* __restrict__ a1d,
    int* __restrict__ gcur, int* __restrict__ binned,
    short* __restrict__ wTg, short* __restrict__ kwTg, short* __restrict__ awTg) {
  const int bid = blockIdx.x;
  const int t = threadIdx.x;
  if (bid >= 2 * NBINB) {                    // ---- wprep part ----
    int i = (bid - 2 * NBINB) * 256 + t;
    if (i < 32768) {                 // proj_w: [256][128] -> wTg [128][256]
      int n = i >> 8, k = i & 255;
      __hip_bfloat16 b = __float2bfloat16(w[k * 128 + n]);
      wTg[i] = *(short*)&b;
    } else if (i < 49152) {          // k_lin_w: [128][128] -> kwTg [128][128]
      int j = i - 32768;
      int n = j >> 7, k = j & 127;
      __hip_bfloat16 b = __float2bfloat16(kw[k * 128 + n]);
      kwTg[j] = *(short*)&b;
    } else if (i < 53248) {          // alpha weights -> awTg [32][128]
      int j = i - 49152;
      int c = j >> 7, k = j & 127;   // c = p*16 + dtype*8 + h
      int p = c >> 4, dt = (c >> 3) & 1, h = c & 7;
      const float* arr = p ? (dt ? a1d : a1s) : (dt ? a0d : a0s);
      float v = ((k >> 4) == h) ? arr[h * 16 + (k & 15)] * 1.44269504f : 0.f;
      __hip_bfloat16 b = __float2bfloat16(v);
      awTg[j] = *(short*)&b;
    }
    return;
  }
  // ---- bin part ----
  const int p = bid >= NBINB;
  const int bx = p ? bid - NBINB : bid;
  const int* __restrict__ ei = p ? ei1 : ei0;
  const int* __restrict__ src = ei;
  const int* __restrict__ dst = ei + EE;
  int* __restrict__ gc = gcur + p * 256;
  int* __restrict__ bn = binned + (size_t)p * NB * CAPB;
  __shared__ int cntL[NB], baseL[NB];
  const int e0 = bx * EBLK;
  const int e1 = min(e0 + EBLK, EE);
  for (int i = t; i < NB; i += 256) cntL[i] = 0;
  __syncthreads();
  int vj[16], bj[16];
#pragma unroll
  for (int j = 0; j < 16; j++) {
    int e = e0 + t + j * 256;
    bj[j] = -1;
    if (e < e1) {
      int d = dst[e];
      int b = d >> BSH;
      int off = atomicAdd(&cntL[b], 1);
      vj[j] = (src[e] << BSH) | (d & 511);
      bj[j] = (b << 14) | off;
    }
  }
  __syncthreads();
  for (int i = t; i < NB; i += 256) baseL[i] = atomicAdd(&gc[i], cntL[i]);
  __syncthreads();
#pragma unroll
  for (int j = 0; j < 16; j++) {
    if (bj[j] >= 0) {
      int b = bj[j] >> 14;
      int off = baseL[b] + (bj[j] & 16383);
      if (off < CAPB) bn[b * CAPB + off] = vj[j];
    }
  }
}

// ---------------- fused: CSR build + projection GEMM ----------------
// blocks [0, 392): bucket -> CSR via LDS staging (full-line int4 bursts).
// blocks [392, 904): MFMA projection, 512 threads, SWAPPED operands:
//   mfma(A=W-frag, B=x-frag) -> D^T, so each lane holds 4 CONSECUTIVE columns
//   of ONE node's xph row. r8 counters showed the old epilogue's 32 scattered
//   2B stores/tile stalled the wave on vmcnt store-drain (VALUBusy 0.08%,
//   Occ 0.5%, WRITE_SIZE +100MB partial-line churn). Now: 8 dwordx2 stores
//   (xph) + 2 dwordx4 (alpha, direct into split [node][8] arrays — packed
//   [node][32] cost k_aggr +60MB fetch in r7). Fragment LDS reads unchanged
//   by the swap; bias via 512B LDS array (keeps VGPR<=128 for 4 waves/SIMD).
#define PWS 264    // wT LDS stride in bf16 elems (528 B, 16B-aligned rows)
#define AWS 136    // awT LDS stride
#define PNT ((NN + 15) / 16)   // 6250 row-tiles

__global__ __launch_bounds__(512) void k_mid(
    const int* __restrict__ gcur, const int* __restrict__ binned,
    int* __restrict__ cnt, int* __restrict__ csr,
    const float* __restrict__ x, const short* __restrict__ wTg,
    const short* __restrict__ awTg, const float* __restrict__ bias,
    __hip_bfloat16* __restrict__ xph,
    float* __restrict__ as0, float* __restrict__ ad0,
    float* __restrict__ as1, float* __restrict__ ad1) {
  __shared__ short wT[128 * PWS];   // proj: w^T bf16 [n][k]; build aliases stage[]
  __shared__ short awT[32 * AWS];   // proj: alpha weights [c][k]; build aliases lc[]
  __shared__ float biasL[128];
  const int bid = blockIdx.x;
  const int tid = threadIdx.x;
  if (bid < NBUILD) {               // ---- build part ----
    int* stage = (int*)wT;          // 16384 ints (65536B of 67584)
    int* lc = (int*)awT;            // 256 ints
    const int p = bid >= 196, b = p ? bid - 196 : bid;
    const int* __restrict__ bn = binned + (size_t)p * NB * CAPB + (size_t)b * CAPB;
    const int n = min(gcur[p * 256 + b], CAPB);
    int* __restrict__ cs = csr + (size_t)p * NNP * CAP;
    const int node0 = b << BSH;
#pragma unroll 1
    for (int half = 0; half < 2; half++) {
      if (tid < 256) lc[tid] = 0;
      __syncthreads();
      for (int i = tid; i < n; i += 512) {
        int v = bn[i];
        int ln = v & 511;
        if ((ln >> 8) == half) {
          int lnh = ln & 255;
          int off = atomicAdd(&lc[lnh], 1);
          if (off < CAP) stage[lnh * CAP + off] = v >> BSH;
        }
      }
      __syncthreads();
      const int nodeH = node0 + half * 256;
      int4* dst4 = (int4*)(cs + (size_t)nodeH * CAP);
      const int4* src4 = (const int4*)stage;
      for (int i = tid; i < 4096; i += 512) dst4[i] = src4[i];  // full-line bursts
      if (tid < 256 && nodeH + tid < NN) cnt[p * NN + nodeH + tid] = lc[tid];
      __syncthreads();
    }
    return;
  }
  // ---- proj part ----
  const int pb = bid - NBUILD;
  for (int i = tid; i < 4096; i += 512) {        // wT fill: 8 iters of short8
    int n = i >> 5, kc = i & 31;
    *(short8*)&wT[n * PWS + kc * 8] = *(const short8*)&wTg[n * 256 + kc * 8];
  }
  {                                               // awT fill: 1 iter
    int n = tid >> 4, kc = tid & 15;
    *(short8*)&awT[n * AWS + kc * 8] = *(const short8*)&awTg[n * 128 + kc * 8];
  }
  if (tid < 128) biasL[tid] = bias[tid];
  const int lane = tid & 63, wave = tid >> 6;    // wave in [0,8)
  const int rowgrp = lane >> 4, lcol = lane & 15;
  // alpha store routing: swapped-MFMA row c = rowgrp*4+r -> dtype=rowgrp>>1,
  // h = (rowgrp&1)*4+r. Pointer select hoisted (per-lane constant).
  float* __restrict__ apP0 = (rowgrp < 2) ? as0 : ad0;
  float* __restrict__ apP1 = (rowgrp < 2) ? as1 : ad1;
  const int hofs = (rowgrp & 1) * 4;
  __syncthreads();
  short* __restrict__ xphS = (short*)xph;
  for (int tile = pb * 8 + wave; tile < PNT; tile += NPROJ * 8) {
    const int r0 = tile * 16;                    // NN%16==0: rows always valid
    const int node = r0 + lcol;
    const float* xr = x + (size_t)node * 256 + rowgrp * 8;
    short8 af[8];
#pragma unroll
    for (int kc = 0; kc < 8; kc++) {
      float4 u0 = *(const float4*)(xr + kc * 32);
      float4 u1 = *(const float4*)(xr + kc * 32 + 4);
      union { short8 v; __hip_bfloat162 h[4]; } u;
      u.h[0] = __float22bfloat162_rn(make_float2(u0.x, u0.y));
      u.h[1] = __float22bfloat162_rn(make_float2(u0.z, u0.w));
      u.h[2] = __float22bfloat162_rn(make_float2(u1.x, u1.y));
      u.h[3] = __float22bfloat162_rn(make_float2(u1.z, u1.w));
      af[kc] = u.v;
    }
#pragma unroll
    for (int ct = 0; ct < 8; ct++) {
      f32x4 acc = {0.f, 0.f, 0.f, 0.f};
#pragma unroll
      for (int kc = 0; kc < 8; kc++) {
        short8 bf = *(const short8*)&wT[(ct * 16 + lcol) * PWS + kc * 32 + rowgrp * 8];
        // SWAPPED: A = W-frag, B = x-frag -> D[n][node] (transposed C layout)
        acc = __builtin_amdgcn_mfma_f32_16x16x32_bf16(bf, af[kc], acc, 0, 0, 0);
      }
      float4 bq = *(const float4*)&biasL[ct * 16 + rowgrp * 4];
      union { __hip_bfloat162 h[2]; int2 d; } st;
      st.h[0] = __float22bfloat162_rn(make_float2(acc[0] + bq.x, acc[1] + bq.y));
      st.h[1] = __float22bfloat162_rn(make_float2(acc[2] + bq.z, acc[3] + bq.w));
      *(int2*)&xphS[(size_t)node * 128 + ct * 16 + rowgrp * 4] = st.d;
    }
    // ---- alpha logits via MFMA (swapped): read tile back (L2-hot) ----
    const short* xb = xphS + (size_t)node * 128 + rowgrp * 8;
    short8 af2[4];
#pragma unroll
    for (int kc = 0; kc < 4; kc++) af2[kc] = *(const short8*)(xb + kc * 32);
#pragma unroll
    for (int ct2 = 0; ct2 < 2; ct2++) {
      f32x4 acc2 = {0.f, 0.f, 0.f, 0.f};
#pragma unroll
      for (int kc = 0; kc < 4; kc++) {
        short8 bfa = *(const short8*)&awT[(ct2 * 16 + lcol) * AWS + kc * 32 + rowgrp * 8];
        acc2 = __builtin_amdgcn_mfma_f32_16x16x32_bf16(bfa, af2[kc], acc2, 0, 0, 0);
      }
      float* __restrict__ ap = ct2 ? apP1 : apP0;
      *(f32x4*)&ap[(size_t)node * 8 + hofs] = acc2;   // 16B store, h {hofs..hofs+3}
    }
  }
}

// ---------------- GAT aggregation: single-pass, one wave per dst node ----------
// (proven structure. Do NOT route the src index or alpha through
// __shfl/ds_bpermute here: old r7 tried it, VALUBusy fell 71->32% but the
// LDS-pipe hop in the gather-address chain made it latency-bound, 158->252us.)
// node via readfirstlane -> CSR walk on the scalar pipe (s_load_dwordx4).
// alpha logits arrive pre-scaled by log2e -> single v_exp_f32 per edge.

#define EDGE_BODY(sv)                                      \
  {                                                        \
    unsigned s = (unsigned)(sv);                           \
    float t = asrc[s * 8u + h];                            \
    __hip_bfloat162 v = xph[s * 64u + lane];               \
    float tt = t + ad;                                     \
    float al = exp2_fast(fmaxf(tt, NEG * tt));             \
    denom += al;                                           \
    float2 f = __bfloat1622float2(v);                      \
    a0 = fmaf(al, f.x, a0);                                \
    a1 = fmaf(al, f.y, a1);                                \
  }

__global__ __launch_bounds__(256) void k_aggr(const __hip_bfloat162* __restrict__ xph,
    const float* __restrict__ as0, const float* __restrict__ ad0,
    const float* __restrict__ as1, const float* __restrict__ ad1,
    const int* __restrict__ cnt, const int* __restrict__ csr,
    __hip_bfloat162* __restrict__ h0, __hip_bfloat162* __restrict__ h1) {
  const int p = blockIdx.y;
  const unsigned lane = threadIdx.x & 63;
  int node = blockIdx.x * 4 + (threadIdx.x >> 6);
  if (node >= NN) return;
  node = __builtin_amdgcn_readfirstlane(node);   // provably wave-uniform
  const float* __restrict__ asrc = p ? as1 : as0;
  const float* __restrict__ adst = p ? ad1 : ad0;
  const int* __restrict__ cs = csr + ((size_t)p * NNP + node) * CAP;
  __hip_bfloat162* __restrict__ hout = p ? h1 : h0;
  const unsigned h = lane >> 3;
  const float ad = adst[(unsigned)node * 8u + h];
  const int deg = min(cnt[p * NN + node], CAP);

  float denom = 1e-16f, a0 = 0.f, a1 = 0.f;
  int e = 0;
  for (; e + 8 <= deg; e += 8) {
    int4 q0 = *(const int4*)&cs[e];       // uniform -> s_load_dwordx4
    int4 q1 = *(const int4*)&cs[e + 4];
    EDGE_BODY(q0.x) EDGE_BODY(q0.y) EDGE_BODY(q0.z) EDGE_BODY(q0.w)
    EDGE_BODY(q1.x) EDGE_BODY(q1.y) EDGE_BODY(q1.z) EDGE_BODY(q1.w)
  }
  for (; e + 4 <= deg; e += 4) {
    int4 q0 = *(const int4*)&cs[e];
    EDGE_BODY(q0.x) EDGE_BODY(q0.y) EDGE_BODY(q0.z) EDGE_BODY(q0.w)
  }
  for (; e < deg; e++) EDGE_BODY(cs[e])
  float inv = 1.f / denom;
  hout[(size_t)node * 64 + lane] =
      __float22bfloat162_rn(make_float2(fmaxf(a0 * inv, 0.f), fmaxf(a1 * inv, 0.f)));
}

// ---------------- semantic attention via MFMA + fused output head ----------------
// kwT staged in LDS (bf16 copy from kwTg); o_m = h_m @ lw in fp32 VALU
// (NOT bf16 MFMA: lw-rounding would land directly on the output) so no 51MB
// h re-read in a final kernel.
#define KWS 136
#define NTILES ((NN + 63) / 64)
#define SEMGX 512

__global__ __launch_bounds__(256) void k_sem(const __hip_bfloat16* __restrict__ h0,
    const __hip_bfloat16* __restrict__ h1, const short* __restrict__ kwTg,
    const float* __restrict__ kb, const float* __restrict__ lw,
    float* __restrict__ ksum, float* __restrict__ o0, float* __restrict__ o1) {
  __shared__ short kwT[128 * KWS];
  __shared__ float red[4][128];
  __shared__ float lwS[512];
  const int tid = threadIdx.x;
  const int m = blockIdx.y;
  const short* __restrict__ hc = (const short*)(m ? h1 : h0);
  float* __restrict__ oc = m ? o1 : o0;
  for (int i = tid; i < 2048; i += 256) {        // 2048 short8 chunks
    int n = i >> 4, kc = i & 15;
    *(short8*)&kwT[n * KWS + kc * 8] = *(const short8*)&kwTg[n * 128 + kc * 8];
  }
  for (int l = tid; l < 512; l += 256) lwS[l] = lw[l];
  const int lane = tid & 63;
  const int wave = tid >> 6;
  const int rowgrp = lane >> 4;
  const int lcol = lane & 15;
  float partial[8] = {};
  float kbv[8];
#pragma unroll
  for (int ct = 0; ct < 8; ct++) kbv[ct] = kb[ct * 16 + lcol];
  __syncthreads();
  for (int tile = blockIdx.x; tile < NTILES; tile += SEMGX) {
    int n0 = tile * 64 + wave * 16;
    int row = n0 + lcol;
    if (row >= NN) row = 0;
    const short* hr = hc + (size_t)row * 128 + rowgrp * 8;
    short8 afrag[4];
#pragma unroll
    for (int kc = 0; kc < 4; kc++) afrag[kc] = *(const short8*)(hr + kc * 32);
    // ---- fused output head: op[c] = sum_k h[row][k] * lw[k*4+c] (fp32) ----
    float op[4] = {0.f, 0.f, 0.f, 0.f};
#pragma unroll
    for (int kc = 0; kc < 4; kc++) {
      union { short8 v; short s[8]; } u;
      u.v = afrag[kc];
#pragma unroll
      for (int j = 0; j < 8; j++) {
        float hv = bf2f(u.s[j]);
        const float4 lv = *(const float4*)&lwS[(kc * 32 + rowgrp * 8 + j) * 4];
        op[0] = fmaf(hv, lv.x, op[0]);
        op[1] = fmaf(hv, lv.y, op[1]);
        op[2] = fmaf(hv, lv.z, op[2]);
        op[3] = fmaf(hv, lv.w, op[3]);
      }
    }
#pragma unroll
    for (int c = 0; c < 4; c++) {   // reduce across the 4 rowgrps (k-chunks)
      op[c] += __shfl_xor(op[c], 16, 64);
      op[c] += __shfl_xor(op[c], 32, 64);
    }
    int orow = n0 + lcol;
    if (rowgrp == 0 && orow < NN) {
      float4 ov = make_float4(op[0], op[1], op[2], op[3]);
      *(float4*)&oc[(size_t)orow * 4] = ov;
    }
    // ---- k-vector path (tanh(h@kw+kb), summed over nodes) ----
#pragma unroll
    for (int ct = 0; ct < 8; ct++) {
      f32x4 acc = {0.f, 0.f, 0.f, 0.f};
#pragma unroll
      for (int kc = 0; kc < 4; kc++) {
        short8 bfrag = *(const short8*)&kwT[(ct * 16 + lcol) * KWS + kc * 32 + rowgrp * 8];
        acc = __builtin_amdgcn_mfma_f32_16x16x32_bf16(afrag[kc], bfrag, acc, 0, 0, 0);
      }
#pragma unroll
      for (int r = 0; r < 4; r++) {
        int node = n0 + rowgrp * 4 + r;
        if (node < NN) partial[ct] += tanh_fast(acc[r] + kbv[ct]);
      }
    }
  }
#pragma unroll
  for (int ct = 0; ct < 8; ct++) {
    partial[ct] += __shfl_xor(partial[ct], 16, 64);
    partial[ct] += __shfl_xor(partial[ct], 32, 64);
  }
  if (lane < 16) {
#pragma unroll
    for (int ct = 0; ct < 8; ct++) red[wave][ct * 16 + lane] = partial[ct];
  }
  __syncthreads();
  if (tid < 128) {
    float s = red[0][tid] + red[1][tid] + red[2][tid] + red[3][tid];
    atomicAdd(&ksum[m * 128 + tid], s);
  }
}

// ---------------- final blend (attn softmax folded in) ----------------
__global__ __launch_bounds__(256) void k_blend(const float* __restrict__ o0,
    const float* __restrict__ o1, const float* __restrict__ lb,
    const float* __restrict__ ksum, const float* __restrict__ q,
    float* __restrict__ out) {
  __shared__ float aw[2];
  const int t = threadIdx.x;
  if (t < 64) {
    float qa = q[t], qb = q[t + 64];
    float s0 = fmaf(ksum[t], qa, ksum[t + 64] * qb);
    float s1 = fmaf(ksum[128 + t], qa, ksum[192 + t] * qb);
#pragma unroll
    for (int off = 1; off < 64; off <<= 1) {
      s0 += __shfl_xor(s0, off, 64);
      s1 += __shfl_xor(s1, off, 64);
    }
    if (t == 0) {
      float l0 = s0 * (1.f / NN), l1 = s1 * (1.f / NN);
      float mx = fmaxf(l0, l1);
      float e0 = __expf(l0 - mx), e1 = __expf(l1 - mx);
      float inv = 1.f / (e0 + e1);
      aw[0] = e0 * inv;
      aw[1] = e1 * inv;
    }
  }
  __syncthreads();
  int i = blockIdx.x * 256 + t;
  if (i < NN * 4)
    out[i] = aw[0] * o0[i] + aw[1] * o1[i] + lb[i & 3];
}

extern "C" void kernel_launch(void* const* d_in, const int* in_sizes, int n_in,
                              void* d_out, int out_size, void* d_ws, size_t ws_size,
                              hipStream_t stream) {
  const float* x      = (const float*)d_in[0];
  const int*   ei0    = (const int*)d_in[1];
  const int*   ei1    = (const int*)d_in[2];
  const float* proj_w = (const float*)d_in[3];
  const float* proj_b = (const float*)d_in[4];
  const float* a0s    = (const float*)d_in[5];
  const float* a0d    = (const float*)d_in[6];
  const float* a1s    = (const float*)d_in[7];
  const float* a1d    = (const float*)d_in[8];
  const float* klw    = (const float*)d_in[9];
  const float* klb    = (const float*)d_in[10];
  const float* q      = (const float*)d_in[11];
  const float* lw     = (const float*)d_in[12];
  const float* lb     = (const float*)d_in[13];
  float* out = (float*)d_out;

  char* ws = (char*)d_ws;
  size_t off = 0;
  auto alloc = [&](size_t bytes) -> void* {
    size_t o = (off + 255) & ~(size_t)255;
    off = o + bytes;
    return (void*)(ws + o);
  };
  __hip_bfloat162* xph = (__hip_bfloat162*)alloc((size_t)NN * 128 * 2);
  __hip_bfloat162* h0  = (__hip_bfloat162*)alloc((size_t)NN * 128 * 2);
  __hip_bfloat162* h1  = (__hip_bfloat162*)alloc((size_t)NN * 128 * 2);
  float* as0  = (float*)alloc((size_t)NN * 8 * 4);
  float* ad0  = (float*)alloc((size_t)NN * 8 * 4);
  float* as1  = (float*)alloc((size_t)NN * 8 * 4);
  float* ad1  = (float*)alloc((size_t)NN * 8 * 4);
  float* ksum = (float*)alloc(256 * 4);            // 1024 B
  int* gcur   = (int*)alloc(2 * 256 * 4);          // contiguous after ksum (2048 B)
  int* cnt    = (int*)alloc((size_t)2 * NN * 4);   // fully written by build — no memset
  int* csr    = (int*)alloc((size_t)2 * NNP * CAP * 4);  // padded rows: unguarded writes
  int* binned = (int*)alloc((size_t)2 * NB * CAPB * 4);
  short* wTg  = (short*)alloc(32768 * 2);
  short* kwTg = (short*)alloc(16384 * 2);
  short* awTg = (short*)alloc(4096 * 2);
  float* o0   = (float*)alloc((size_t)NN * 4 * 4);
  float* o1   = (float*)alloc((size_t)NN * 4 * 4);

  // zero ksum + gcur only (cnt is fully overwritten by the build phase)
  hipMemsetAsync(ksum, 0, 256 * 4 + 2 * 256 * 4, stream);

  k_prep<<<dim3(2 * NBINB + NPREPW), 256, 0, stream>>>(ei0, ei1, proj_w, klw,
                                                       a0s, a0d, a1s, a1d,
                                                       gcur, binned, wTg, kwTg, awTg);
  k_mid<<<dim3(NBUILD + NPROJ), 512, 0, stream>>>(gcur, binned, cnt, csr,
                                                  x, wTg, awTg, proj_b,
                                                  (__hip_bfloat16*)xph,
                                                  as0, ad0, as1, ad1);
  k_aggr<<<dim3((NN + 3) / 4, 2), 256, 0, stream>>>(xph, as0, ad0, as1, ad1,
                                                    cnt, csr, h0, h1);
  k_sem<<<dim3(SEMGX, 2), 256, 0, stream>>>((const __hip_bfloat16*)h0,
                                            (const __hip_bfloat16*)h1, kwTg, klb, lw,
                                            ksum, o0, o1);
  k_blend<<<dim3((NN * 4 + 255) / 256), 256, 0, stream>>>(o0, o1, lb, ksum, q, out);
}

// Round 10
// 503.913 us; speedup vs baseline: 1.0399x; 1.0399x over previous
//
#include <hip/hip_runtime.h>
#include <hip/hip_bf16.h>

#define NN 100000
#define EE 1600000
#define HID 128
#define NEG 0.2f
#define CAP 64     // fixed CSR capacity per node (avg deg 16, P(deg>64) ~ 1e-19)
#define BSH 9      // coarse bucket = dst >> 9 (512 nodes/bucket)
#define NB 196     // ceil(NN / 512)
#define NNP (NB * 512)  // csr row padding (100352) so build writes are unguarded
#define CAPB 9216  // per-bucket edge capacity (mean 8192, sigma~90 -> 11 sigma)
#define EBLK 4096  // edges per bin block (391 blocks/path)
#define NBINB 391  // bin blocks per path
#define NBUILD 392 // build blocks (196 buckets x 2 paths)
#define NPROJ 512  // proj blocks in fused k_mid
#define NPREPW 208 // wprep blocks: (32768+16384+4096)/256

typedef __attribute__((ext_vector_type(8))) short short8;
typedef __attribute__((ext_vector_type(4))) float f32x4;

static __device__ __forceinline__ float bf2f(short s) {
  union { float f; unsigned u; } c;
  c.u = ((unsigned)(unsigned short)s) << 16;
  return c.f;
}

// raw v_exp_f32: computes 2^x in one instruction (no mul-by-log2e preamble).
static __device__ __forceinline__ float exp2_fast(float x) {
  float r;
  asm("v_exp_f32 %0, %1" : "=v"(r) : "v"(x));
  return r;
}

// fast tanh: 1 - 2/(2^(2x*log2e)+1); clamp keeps exp in range, rcp approx ok.
static __device__ __forceinline__ float tanh_fast(float x) {
  float a = fminf(fmaxf(x * 2.885390082f, -40.f), 40.f);  // 2*log2(e)*x
  float e = exp2_fast(a);
  float r = __builtin_amdgcn_rcpf(e + 1.f);
  return fmaf(-2.f, r, 1.f);
}

// ---------------- fused: edge binning + weight pre-transpose ----------------
// blocks [0, 782): bin edges by coarse dst bucket. Register-stash counting
//   pass, then IN-LDS COUNTING SORT so the binned[] writes go out with
//   consecutive threads -> consecutive addresses (runs of ~21/bucket). The
//   old direct scatter issued 4B stores across 196 bucket regions: ~16x
//   write-allocate churn on 14.7MB logical — same pathology measured on
//   k_edges (r2) and csr (r6). One-phase global scatter = 220us (r2): keep
//   two-phase.
// blocks [782, 990): transpose proj_w / k_lin_w to bf16; build awTg — the
//   32x128 block-diagonal alpha-weight (bf16, pre-scaled by log2e) for the
//   MFMA alpha-logit computation (r6: serial shuffle butterfly was the proj
//   bottleneck). Col c = p*16 + dtype*8 + h; row k nonzero iff k>>4 == h.
__global__ __launch_bounds__(256) void k_prep(const int* __restrict__ ei0,
    const int* __restrict__ ei1, const float* __restrict__ w,
    const float* __restrict__ kw,
    const float* __restrict__ a0s, const float* __restrict__ a0d,
    const float* __restrict__ a1s, const float* __restrict__ a1d,
    int* __restrict__ gcur, int* __restrict__ binned,
    short* __restrict__ wTg, short* __restrict__ kwTg, short* __restrict__ awTg) {
  const int bid = blockIdx.x;
  const int t = threadIdx.x;
  if (bid >= 2 * NBINB) {                    // ---- wprep part ----
    int i = (bid - 2 * NBINB) * 256 + t;
    if (i < 32768) {                 // proj_w: [256][128] -> wTg [128][256]
      int n = i >> 8, k = i & 255;
      __hip_bfloat16 b = __float2bfloat16(w[k * 128 + n]);
      wTg[i] = *(short*)&b;
    } else if (i < 49152) {          // k_lin_w: [128][128] -> kwTg [128][128]
      int j = i - 32768;
      int n = j >> 7, k = j & 127;
      __hip_bfloat16 b = __float2bfloat16(kw[k * 128 + n]);
      kwTg[j] = *(short*)&b;
    } else if (i < 53248) {          // alpha weights -> awTg [32][128]
      int j = i - 49152;
      int c = j >> 7, k = j & 127;   // c = p*16 + dtype*8 + h
      int p = c >> 4, dt = (c >> 3) & 1, h = c & 7;
      const float* arr = p ? (dt ? a1d : a1s) : (dt ? a0d : a0s);
      float v = ((k >> 4) == h) ? arr[h * 16 + (k & 15)] * 1.44269504f : 0.f;
      __hip_bfloat16 b = __float2bfloat16(v);
      awTg[j] = *(short*)&b;
    }
    return;
  }
  // ---- bin part (counting sort in LDS) ----
  const int p = bid >= NBINB;
  const int bx = p ? bid - NBINB : bid;
  const int* __restrict__ ei = p ? ei1 : ei0;
  const int* __restrict__ src = ei;
  const int* __restrict__ dst = ei + EE;
  int* __restrict__ gc = gcur + p * 256;
  int* __restrict__ bn = binned + (size_t)p * NB * CAPB;
  __shared__ int cntL[NB], startL[NB], sbase[NB];
  __shared__ int scanT[256];
  __shared__ int sortV[EBLK];       // 16 KB: values ordered by bucket
  __shared__ short sortB[EBLK];     // 8 KB: bucket id per slot
  const int e0 = bx * EBLK;
  const int e1 = min(e0 + EBLK, EE);
  const int n = e1 - e0;
  for (int i = t; i < NB; i += 256) cntL[i] = 0;
  __syncthreads();
  int vj[16], bj[16];
#pragma unroll
  for (int j = 0; j < 16; j++) {
    int e = e0 + t + j * 256;
    bj[j] = -1;
    if (e < e1) {
      int d = dst[e];
      int b = d >> BSH;
      int off = atomicAdd(&cntL[b], 1);
      vj[j] = (src[e] << BSH) | (d & 511);
      bj[j] = (b << 14) | off;
    }
  }
  __syncthreads();
  // exclusive scan of cntL (Hillis-Steele over 256, NB=196<=256)
  scanT[t] = (t < NB) ? cntL[t] : 0;
  __syncthreads();
  for (int ofs = 1; ofs < 256; ofs <<= 1) {
    int v = scanT[t];
    int u = (t >= ofs) ? scanT[t - ofs] : 0;
    __syncthreads();
    scanT[t] = v + u;
    __syncthreads();
  }
  if (t < NB) {
    int excl = scanT[t] - cntL[t];
    startL[t] = excl;
    int gb = atomicAdd(&gc[t], cntL[t]);
    sbase[t] = t * CAPB + gb - excl;   // slot s in bucket t -> global sbase[t]+s
  }
  __syncthreads();
  // scatter into dense bucket-ordered LDS
#pragma unroll
  for (int j = 0; j < 16; j++) {
    if (bj[j] >= 0) {
      int b = bj[j] >> 14;
      int s = startL[b] + (bj[j] & 16383);
      sortV[s] = vj[j];
      sortB[s] = (short)b;
    }
  }
  __syncthreads();
  // coalesced write-out: consecutive s -> consecutive global addresses
  for (int s = t; s < n; s += 256) {
    int b = sortB[s];
    int ga = sbase[b] + s;
    if (ga - b * CAPB < CAPB) bn[ga] = sortV[s];
  }
}

// ---------------- fused: CSR build + projection GEMM (r8 form, best: 512us) --
// blocks [0, 392): bucket -> CSR via LDS staging (full-line int4 bursts).
// blocks [392, 904): MFMA projection, 512 threads. B-frags from LDS (L2-direct
//   measured +58us WORSE in r3). Epilogue: store bf16 xph tile, read it back
//   (L2-hot), 8 MFMA vs block-diag awT -> alpha logits into SPLIT [node][8]
//   arrays (packed [node][32] cost k_aggr +60MB fetch in r7; swapped-operand
//   variant measured +7us in r9 — keep THIS orientation).
#define PWS 264    // wT LDS stride in bf16 elems (528 B, 16B-aligned rows)
#define AWS 136    // awT LDS stride
#define PNT ((NN + 15) / 16)   // 6250 row-tiles

__global__ __launch_bounds__(512) void k_mid(
    const int* __restrict__ gcur, const int* __restrict__ binned,
    int* __restrict__ cnt, int* __restrict__ csr,
    const float* __restrict__ x, const short* __restrict__ wTg,
    const short* __restrict__ awTg, const float* __restrict__ bias,
    __hip_bfloat16* __restrict__ xph,
    float* __restrict__ as0, float* __restrict__ ad0,
    float* __restrict__ as1, float* __restrict__ ad1) {
  __shared__ short wT[128 * PWS];   // proj: w^T bf16 [n][k]; build aliases stage[]
  __shared__ short awT[32 * AWS];   // proj: alpha weights [c][k]; build aliases lc[]
  const int bid = blockIdx.x;
  const int tid = threadIdx.x;
  if (bid < NBUILD) {               // ---- build part ----
    int* stage = (int*)wT;          // 16384 ints (65536B of 67584)
    int* lc = (int*)awT;            // 256 ints
    const int p = bid >= 196, b = p ? bid - 196 : bid;
    const int* __restrict__ bn = binned + (size_t)p * NB * CAPB + (size_t)b * CAPB;
    const int n = min(gcur[p * 256 + b], CAPB);
    int* __restrict__ cs = csr + (size_t)p * NNP * CAP;
    const int node0 = b << BSH;
#pragma unroll 1
    for (int half = 0; half < 2; half++) {
      if (tid < 256) lc[tid] = 0;
      __syncthreads();
      for (int i = tid; i < n; i += 512) {
        int v = bn[i];
        int ln = v & 511;
        if ((ln >> 8) == half) {
          int lnh = ln & 255;
          int off = atomicAdd(&lc[lnh], 1);
          if (off < CAP) stage[lnh * CAP + off] = v >> BSH;
        }
      }
      __syncthreads();
      const int nodeH = node0 + half * 256;
      int4* dst4 = (int4*)(cs + (size_t)nodeH * CAP);
      const int4* src4 = (const int4*)stage;
      for (int i = tid; i < 4096; i += 512) dst4[i] = src4[i];  // full-line bursts
      if (tid < 256 && nodeH + tid < NN) cnt[p * NN + nodeH + tid] = lc[tid];
      __syncthreads();
    }
    return;
  }
  // ---- proj part ----
  const int pb = bid - NBUILD;
  for (int i = tid; i < 4096; i += 512) {        // wT fill: 8 iters of short8
    int n = i >> 5, kc = i & 31;
    *(short8*)&wT[n * PWS + kc * 8] = *(const short8*)&wTg[n * 256 + kc * 8];
  }
  {                                               // awT fill: 1 iter
    int n = tid >> 4, kc = tid & 15;
    *(short8*)&awT[n * AWS + kc * 8] = *(const short8*)&awTg[n * 128 + kc * 8];
  }
  const int lane = tid & 63, wave = tid >> 6;    // wave in [0,8)
  const int rowgrp = lane >> 4, lcol = lane & 15;
  const int hh = lcol & 7;
  float* __restrict__ apA = (lcol & 8) ? ad0 : as0;   // ct2=0 -> path 0
  float* __restrict__ apB = (lcol & 8) ? ad1 : as1;   // ct2=1 -> path 1
  float bv[8];
#pragma unroll
  for (int ct = 0; ct < 8; ct++) bv[ct] = bias[ct * 16 + lcol];
  __syncthreads();
  short* __restrict__ xphS = (short*)xph;
  for (int tile = pb * 8 + wave; tile < PNT; tile += NPROJ * 8) {
    const int r0 = tile * 16;                    // NN%16==0: rows always valid
    const float* xr = x + (size_t)(r0 + lcol) * 256 + rowgrp * 8;
    short8 af[8];
#pragma unroll
    for (int kc = 0; kc < 8; kc++) {
      float4 u0 = *(const float4*)(xr + kc * 32);
      float4 u1 = *(const float4*)(xr + kc * 32 + 4);
      union { short8 v; __hip_bfloat162 h[4]; } u;
      u.h[0] = __float22bfloat162_rn(make_float2(u0.x, u0.y));
      u.h[1] = __float22bfloat162_rn(make_float2(u0.z, u0.w));
      u.h[2] = __float22bfloat162_rn(make_float2(u1.x, u1.y));
      u.h[3] = __float22bfloat162_rn(make_float2(u1.z, u1.w));
      af[kc] = u.v;
    }
#pragma unroll
    for (int ct = 0; ct < 8; ct++) {
      f32x4 acc = {0.f, 0.f, 0.f, 0.f};
#pragma unroll
      for (int kc = 0; kc < 8; kc++) {
        short8 bf = *(const short8*)&wT[(ct * 16 + lcol) * PWS + kc * 32 + rowgrp * 8];
        acc = __builtin_amdgcn_mfma_f32_16x16x32_bf16(af[kc], bf, acc, 0, 0, 0);
      }
#pragma unroll
      for (int r = 0; r < 4; r++) {
        int orow = r0 + rowgrp * 4 + r;   // C/D: row = (lane>>4)*4 + reg
        __hip_bfloat16 ob = __float2bfloat16(acc[r] + bv[ct]);
        xphS[(size_t)orow * 128 + ct * 16 + lcol] = *(short*)&ob;
      }
    }
    // ---- alpha logits via MFMA: read tile back (L2-hot) x block-diag awT ----
    const short* xb = xphS + (size_t)(r0 + lcol) * 128 + rowgrp * 8;
    short8 af2[4];
#pragma unroll
    for (int kc = 0; kc < 4; kc++) af2[kc] = *(const short8*)(xb + kc * 32);
#pragma unroll
    for (int ct2 = 0; ct2 < 2; ct2++) {
      f32x4 acc2 = {0.f, 0.f, 0.f, 0.f};
#pragma unroll
      for (int kc = 0; kc < 4; kc++) {
        short8 bfa = *(const short8*)&awT[(ct2 * 16 + lcol) * AWS + kc * 32 + rowgrp * 8];
        acc2 = __builtin_amdgcn_mfma_f32_16x16x32_bf16(af2[kc], bfa, acc2, 0, 0, 0);
      }
      float* __restrict__ ap = ct2 ? apB : apA;
#pragma unroll
      for (int r = 0; r < 4; r++)
        ap[(size_t)(r0 + rowgrp * 4 + r) * 8 + hh] = acc2[r];
    }
  }
}

// ---------------- GAT aggregation: single-pass, one wave per dst node ----------
// (proven structure. Do NOT route the src index or alpha through
// __shfl/ds_bpermute here: old r7 tried it, VALUBusy fell 71->32% but the
// LDS-pipe hop in the gather-address chain made it latency-bound, 158->252us.)
// node via readfirstlane -> CSR walk on the scalar pipe (s_load_dwordx4).
// alpha logits arrive pre-scaled by log2e -> single v_exp_f32 per edge.

#define EDGE_BODY(sv)                                      \
  {                                                        \
    unsigned s = (unsigned)(sv);                           \
    float t = asrc[s * 8u + h];                            \
    __hip_bfloat162 v = xph[s * 64u + lane];               \
    float tt = t + ad;                                     \
    float al = exp2_fast(fmaxf(tt, NEG * tt));             \
    denom += al;                                           \
    float2 f = __bfloat1622float2(v);                      \
    a0 = fmaf(al, f.x, a0);                                \
    a1 = fmaf(al, f.y, a1);                                \
  }

__global__ __launch_bounds__(256) void k_aggr(const __hip_bfloat162* __restrict__ xph,
    const float* __restrict__ as0, const float* __restrict__ ad0,
    const float* __restrict__ as1, const float* __restrict__ ad1,
    const int* __restrict__ cnt, const int* __restrict__ csr,
    __hip_bfloat162* __restrict__ h0, __hip_bfloat162* __restrict__ h1) {
  const int p = blockIdx.y;
  const unsigned lane = threadIdx.x & 63;
  int node = blockIdx.x * 4 + (threadIdx.x >> 6);
  if (node >= NN) return;
  node = __builtin_amdgcn_readfirstlane(node);   // provably wave-uniform
  const float* __restrict__ asrc = p ? as1 : as0;
  const float* __restrict__ adst = p ? ad1 : ad0;
  const int* __restrict__ cs = csr + ((size_t)p * NNP + node) * CAP;
  __hip_bfloat162* __restrict__ hout = p ? h1 : h0;
  const unsigned h = lane >> 3;
  const float ad = adst[(unsigned)node * 8u + h];
  const int deg = min(cnt[p * NN + node], CAP);

  float denom = 1e-16f, a0 = 0.f, a1 = 0.f;
  int e = 0;
  for (; e + 8 <= deg; e += 8) {
    int4 q0 = *(const int4*)&cs[e];       // uniform -> s_load_dwordx4
    int4 q1 = *(const int4*)&cs[e + 4];
    EDGE_BODY(q0.x) EDGE_BODY(q0.y) EDGE_BODY(q0.z) EDGE_BODY(q0.w)
    EDGE_BODY(q1.x) EDGE_BODY(q1.y) EDGE_BODY(q1.z) EDGE_BODY(q1.w)
  }
  for (; e + 4 <= deg; e += 4) {
    int4 q0 = *(const int4*)&cs[e];
    EDGE_BODY(q0.x) EDGE_BODY(q0.y) EDGE_BODY(q0.z) EDGE_BODY(q0.w)
  }
  for (; e < deg; e++) EDGE_BODY(cs[e])
  float inv = 1.f / denom;
  hout[(size_t)node * 64 + lane] =
      __float22bfloat162_rn(make_float2(fmaxf(a0 * inv, 0.f), fmaxf(a1 * inv, 0.f)));
}

// ---------------- semantic attention via MFMA + fused output head ----------------
// kwT staged in LDS (bf16 copy from kwTg); o_m = h_m @ lw in fp32 VALU
// (NOT bf16 MFMA: lw-rounding would land directly on the output) so no 51MB
// h re-read in a final kernel.
#define KWS 136
#define NTILES ((NN + 63) / 64)
#define SEMGX 512

__global__ __launch_bounds__(256) void k_sem(const __hip_bfloat16* __restrict__ h0,
    const __hip_bfloat16* __restrict__ h1, const short* __restrict__ kwTg,
    const float* __restrict__ kb, const float* __restrict__ lw,
    float* __restrict__ ksum, float* __restrict__ o0, float* __restrict__ o1) {
  __shared__ short kwT[128 * KWS];
  __shared__ float red[4][128];
  __shared__ float lwS[512];
  const int tid = threadIdx.x;
  const int m = blockIdx.y;
  const short* __restrict__ hc = (const short*)(m ? h1 : h0);
  float* __restrict__ oc = m ? o1 : o0;
  for (int i = tid; i < 2048; i += 256) {        // 2048 short8 chunks
    int n = i >> 4, kc = i & 15;
    *(short8*)&kwT[n * KWS + kc * 8] = *(const short8*)&kwTg[n * 128 + kc * 8];
  }
  for (int l = tid; l < 512; l += 256) lwS[l] = lw[l];
  const int lane = tid & 63;
  const int wave = tid >> 6;
  const int rowgrp = lane >> 4;
  const int lcol = lane & 15;
  float partial[8] = {};
  float kbv[8];
#pragma unroll
  for (int ct = 0; ct < 8; ct++) kbv[ct] = kb[ct * 16 + lcol];
  __syncthreads();
  for (int tile = blockIdx.x; tile < NTILES; tile += SEMGX) {
    int n0 = tile * 64 + wave * 16;
    int row = n0 + lcol;
    if (row >= NN) row = 0;
    const short* hr = hc + (size_t)row * 128 + rowgrp * 8;
    short8 afrag[4];
#pragma unroll
    for (int kc = 0; kc < 4; kc++) afrag[kc] = *(const short8*)(hr + kc * 32);
    // ---- fused output head: op[c] = sum_k h[row][k] * lw[k*4+c] (fp32) ----
    float op[4] = {0.f, 0.f, 0.f, 0.f};
#pragma unroll
    for (int kc = 0; kc < 4; kc++) {
      union { short8 v; short s[8]; } u;
      u.v = afrag[kc];
#pragma unroll
      for (int j = 0; j < 8; j++) {
        float hv = bf2f(u.s[j]);
        const float4 lv = *(const float4*)&lwS[(kc * 32 + rowgrp * 8 + j) * 4];
        op[0] = fmaf(hv, lv.x, op[0]);
        op[1] = fmaf(hv, lv.y, op[1]);
        op[2] = fmaf(hv, lv.z, op[2]);
        op[3] = fmaf(hv, lv.w, op[3]);
      }
    }
#pragma unroll
    for (int c = 0; c < 4; c++) {   // reduce across the 4 rowgrps (k-chunks)
      op[c] += __shfl_xor(op[c], 16, 64);
      op[c] += __shfl_xor(op[c], 32, 64);
    }
    int orow = n0 + lcol;
    if (rowgrp == 0 && orow < NN) {
      float4 ov = make_float4(op[0], op[1], op[2], op[3]);
      *(float4*)&oc[(size_t)orow * 4] = ov;
    }
    // ---- k-vector path (tanh(h@kw+kb), summed over nodes) ----
#pragma unroll
    for (int ct = 0; ct < 8; ct++) {
      f32x4 acc = {0.f, 0.f, 0.f, 0.f};
#pragma unroll
      for (int kc = 0; kc < 4; kc++) {
        short8 bfrag = *(const short8*)&kwT[(ct * 16 + lcol) * KWS + kc * 32 + rowgrp * 8];
        acc = __builtin_amdgcn_mfma_f32_16x16x32_bf16(afrag[kc], bfrag, acc, 0, 0, 0);
      }
#pragma unroll
      for (int r = 0; r < 4; r++) {
        int node = n0 + rowgrp * 4 + r;
        if (node < NN) partial[ct] += tanh_fast(acc[r] + kbv[ct]);
      }
    }
  }
#pragma unroll
  for (int ct = 0; ct < 8; ct++) {
    partial[ct] += __shfl_xor(partial[ct], 16, 64);
    partial[ct] += __shfl_xor(partial[ct], 32, 64);
  }
  if (lane < 16) {
#pragma unroll
    for (int ct = 0; ct < 8; ct++) red[wave][ct * 16 + lane] = partial[ct];
  }
  __syncthreads();
  if (tid < 128) {
    float s = red[0][tid] + red[1][tid] + red[2][tid] + red[3][tid];
    atomicAdd(&ksum[m * 128 + tid], s);
  }
}

// ---------------- final blend (attn softmax folded in) ----------------
__global__ __launch_bounds__(256) void k_blend(const float* __restrict__ o0,
    const float* __restrict__ o1, const float* __restrict__ lb,
    const float* __restrict__ ksum, const float* __restrict__ q,
    float* __restrict__ out) {
  __shared__ float aw[2];
  const int t = threadIdx.x;
  if (t < 64) {
    float qa = q[t], qb = q[t + 64];
    float s0 = fmaf(ksum[t], qa, ksum[t + 64] * qb);
    float s1 = fmaf(ksum[128 + t], qa, ksum[192 + t] * qb);
#pragma unroll
    for (int off = 1; off < 64; off <<= 1) {
      s0 += __shfl_xor(s0, off, 64);
      s1 += __shfl_xor(s1, off, 64);
    }
    if (t == 0) {
      float l0 = s0 * (1.f / NN), l1 = s1 * (1.f / NN);
      float mx = fmaxf(l0, l1);
      float e0 = __expf(l0 - mx), e1 = __expf(l1 - mx);
      float inv = 1.f / (e0 + e1);
      aw[0] = e0 * inv;
      aw[1] = e1 * inv;
    }
  }
  __syncthreads();
  int i = blockIdx.x * 256 + t;
  if (i < NN * 4)
    out[i] = aw[0] * o0[i] + aw[1] * o1[i] + lb[i & 3];
}

extern "C" void kernel_launch(void* const* d_in, const int* in_sizes, int n_in,
                              void* d_out, int out_size, void* d_ws, size_t ws_size,
                              hipStream_t stream) {
  const float* x      = (const float*)d_in[0];
  const int*   ei0    = (const int*)d_in[1];
  const int*   ei1    = (const int*)d_in[2];
  const float* proj_w = (const float*)d_in[3];
  const float* proj_b = (const float*)d_in[4];
  const float* a0s    = (const float*)d_in[5];
  const float* a0d    = (const float*)d_in[6];
  const float* a1s    = (const float*)d_in[7];
  const float* a1d    = (const float*)d_in[8];
  const float* klw    = (const float*)d_in[9];
  const float* klb    = (const float*)d_in[10];
  const float* q      = (const float*)d_in[11];
  const float* lw     = (const float*)d_in[12];
  const float* lb     = (const float*)d_in[13];
  float* out = (float*)d_out;

  char* ws = (char*)d_ws;
  size_t off = 0;
  auto alloc = [&](size_t bytes) -> void* {
    size_t o = (off + 255) & ~(size_t)255;
    off = o + bytes;
    return (void*)(ws + o);
  };
  __hip_bfloat162* xph = (__hip_bfloat162*)alloc((size_t)NN * 128 * 2);
  __hip_bfloat162* h0  = (__hip_bfloat162*)alloc((size_t)NN * 128 * 2);
  __hip_bfloat162* h1  = (__hip_bfloat162*)alloc((size_t)NN * 128 * 2);
  float* as0  = (float*)alloc((size_t)NN * 8 * 4);
  float* ad0  = (float*)alloc((size_t)NN * 8 * 4);
  float* as1  = (float*)alloc((size_t)NN * 8 * 4);
  float* ad1  = (float*)alloc((size_t)NN * 8 * 4);
  float* ksum = (float*)alloc(256 * 4);            // 1024 B
  int* gcur   = (int*)alloc(2 * 256 * 4);          // contiguous after ksum (2048 B)
  int* cnt    = (int*)alloc((size_t)2 * NN * 4);   // fully written by build — no memset
  int* csr    = (int*)alloc((size_t)2 * NNP * CAP * 4);  // padded rows: unguarded writes
  int* binned = (int*)alloc((size_t)2 * NB * CAPB * 4);
  short* wTg  = (short*)alloc(32768 * 2);
  short* kwTg = (short*)alloc(16384 * 2);
  short* awTg = (short*)alloc(4096 * 2);
  float* o0   = (float*)alloc((size_t)NN * 4 * 4);
  float* o1   = (float*)alloc((size_t)NN * 4 * 4);

  // zero ksum + gcur only (cnt is fully overwritten by the build phase)
  hipMemsetAsync(ksum, 0, 256 * 4 + 2 * 256 * 4, stream);

  k_prep<<<dim3(2 * NBINB + NPREPW), 256, 0, stream>>>(ei0, ei1, proj_w, klw,
                                                       a0s, a0d, a1s, a1d,
                                                       gcur, binned, wTg, kwTg, awTg);
  k_mid<<<dim3(NBUILD + NPROJ), 512, 0, stream>>>(gcur, binned, cnt, csr,
                                                  x, wTg, awTg, proj_b,
                                                  (__hip_bfloat16*)xph,
                                                  as0, ad0, as1, ad1);
  k_aggr<<<dim3((NN + 3) / 4, 2), 256, 0, stream>>>(xph, as0, ad0, as1, ad1,
                                                    cnt, csr, h0, h1);
  k_sem<<<dim3(SEMGX, 2), 256, 0, stream>>>((const __hip_bfloat16*)h0,
                                            (const __hip_bfloat16*)h1, kwTg, klb, lw,
                                            ksum, o0, o1);
  k_blend<<<dim3((NN * 4 + 255) / 256), 256, 0, stream>>>(o0, o1, lb, ksum, q, out);
}